// Round 29
// baseline (76.370 us; speedup 1.0000x reference)
//
#include <hip/hip_runtime.h>
#include <stdint.h>

// GAT: N=4096, F_in=512, H=8, F_out=64.
// P_ij = A_i·max(E1_j, R_i·E2_j)·adj, R_i = e^{-0.8 s_i}; A_i cancels in softmax.
// Round 29: re-partition. K1 = prep_w + adj-pack fused (independent work; pack gets
// all 256 CUs -> its per-CU request-queue cap stops binding). K2 = proj+sd standalone
// with 2-way kh-split (2x TLP) + fp16 Xh. K3 = gat (r23 form) unchanged.

#define NN 4096
#define FIN 512
#define NH 8
#define FO 64

typedef _Float16 f16x8 __attribute__((ext_vector_type(8)));
typedef _Float16 f16x2 __attribute__((ext_vector_type(2)));
typedef __attribute__((ext_vector_type(4))) float f32x4;

union H8 { f16x8 v; f16x2 p[4]; unsigned u[4]; };
union U2 { unsigned u; f16x2 v; };

__device__ __forceinline__ unsigned short f2h(float f) {
  _Float16 h = (_Float16)f;               // RNE
  return __builtin_bit_cast(unsigned short, h);
}

// ---------------- K1: prep_w + adj-pack (independent; pack spans the machine) -----
__global__ __launch_bounds__(256) void prep_pack_kernel(
    const float* __restrict__ W, const float* __restrict__ a, const float* __restrict__ X,
    const int* __restrict__ adj,
    unsigned short* __restrict__ WbT, unsigned short* __restrict__ WAh,
    unsigned short* __restrict__ Xh, unsigned* __restrict__ adjbits) {
  int bid = blockIdx.x, tid = threadIdx.x;
  if (bid < 1024) {                       // W[h][k][o] -> WbT[h][o][k], coalesced READ
    int item = bid * 256 + tid;           // 262144 items = (h,k,o)
    int o = item & 63, k = (item >> 6) & 511, h = item >> 15;
    WbT[h * 32768 + o * 512 + k] = f2h(W[h * 32768 + k * 64 + o]);
  } else if (bid < 1056) {                // wa[t][k] = sum_o W[h][k][o]*a[h][which*64+o]
    int item = (bid - 1024) * 256 + tid;  // 8192 items: t = h*2+which, k
    int h = item >> 10, which = (item >> 9) & 1, k = item & 511;
    const float4* wp = (const float4*)(W + ((size_t)h * FIN + k) * FO);
    const float4* ap = (const float4*)(a + h * 128 + which * 64);
    float s = 0.f;
#pragma unroll
    for (int o4 = 0; o4 < 16; ++o4) {
      float4 w4 = wp[o4], a4 = ap[o4];
      s += w4.x * a4.x + w4.y * a4.y + w4.z * a4.z + w4.w * a4.w;
    }
    WAh[(h * 2 + which) * FIN + k] = f2h(s);
  } else if (bid < 3104) {                // X -> fp16, float4/thread
    int item = (bid - 1056) * 256 + tid;  // 524288 items
    float4 v = ((const float4*)X)[item];
    ushort4 o;
    o.x = f2h(v.x); o.y = f2h(v.y); o.z = f2h(v.z); o.w = f2h(v.w);
    ((ushort4*)Xh)[item] = o;
  } else {                                // adj-pack: coalesced reads AND writes
    int item = (bid - 3104) * 256 + tid;  // item = r*128 + jt (524288 items)
    const int4* p = (const int4*)(adj + (size_t)item * 32);   // own 128B chunk
    unsigned bits = 0;
#pragma unroll
    for (int b = 0; b < 8; ++b) {         // 8 contiguous int4s, all in flight
      int4 v = p[b];
      bits |= (unsigned)(v.x & 1) << (4 * b);
      bits |= (unsigned)(v.y & 1) << (4 * b + 1);
      bits |= (unsigned)(v.z & 1) << (4 * b + 2);
      bits |= (unsigned)(v.w & 1) << (4 * b + 3);
    }
    adjbits[item] = bits;                 // row-major [r][jt]: coalesced store
  }
}

// ---------------- K2: proj (2-way kh-split) + sd, fp16 Xh -------------------------
// D layout (16x16x32): col = lane&15, row = (lane>>4)*4 + reg   [m89]
__global__ __launch_bounds__(512, 4) void proj_sd_kernel(
    const unsigned short* __restrict__ Xh, const unsigned short* __restrict__ WbT,
    const unsigned short* __restrict__ WAh,
    unsigned short* __restrict__ Whfrag, float* __restrict__ Rf,
    unsigned short* __restrict__ E1h, unsigned short* __restrict__ E2h) {
  __shared__ float red[4 * 64 * 20];      // 20KB partial store
  int lane = threadIdx.x & 63, wave = threadIdx.x >> 6;
  int row16 = lane & 15, grp = lane >> 4;
  int bx = blockIdx.x;
  if (bx >= 512) {                        // sd: [s,d]x8 = Xh @ WA  (16 cols, K=512)
    int i0 = ((bx - 512) * 8 + wave) * 16;
    if (i0 >= NN) return;
    f32x4 acc = {0, 0, 0, 0};
    const unsigned short* xb = Xh + (size_t)(i0 + row16) * FIN + grp * 8;
    const unsigned short* wb = WAh + row16 * FIN + grp * 8;
#pragma unroll
    for (int k0 = 0; k0 < FIN; k0 += 32)
      acc = __builtin_amdgcn_mfma_f32_16x16x32_f16(*(const f16x8*)(xb + k0),
                                                   *(const f16x8*)(wb + k0), acc, 0, 0, 0);
    int hh = row16 >> 1;
#pragma unroll
    for (int reg = 0; reg < 4; ++reg) {
      int rr = i0 + grp * 4 + reg;
      float v = acc[reg];
      if (row16 & 1) {                    // d -> col tables fp16, PRE-HALVED
        E1h[hh * NN + rr] = f2h(0.5f * __expf(v));
        E2h[hh * NN + rr] = f2h(0.5f * __expf(0.2f * v));
      } else {                            // s -> row table R = e^{-0.8 s}
        Rf[hh * NN + rr] = __expf(-0.8f * v);
      }
    }
    return;
  }
  int kh = wave >> 2, jb = wave & 3;
  int job = bx * 4 + jb;                  // 2048 jobs = 256 rowtiles x 8 heads
  int h = job & 7, rt = job >> 3;
  int i0 = rt * 16;
  f32x4 acc[4] = {{0,0,0,0},{0,0,0,0},{0,0,0,0},{0,0,0,0}};
  const unsigned short* xb = Xh + (size_t)(i0 + row16) * FIN + kh * 256 + grp * 8;
  const unsigned short* wb = WbT + h * (FO * FIN) + row16 * FIN + kh * 256 + grp * 8;
#pragma unroll
  for (int k0 = 0; k0 < 256; k0 += 32) {
    f16x8 af = *(const f16x8*)(xb + k0);
#pragma unroll
    for (int cb = 0; cb < 4; ++cb)
      acc[cb] = __builtin_amdgcn_mfma_f32_16x16x32_f16(
          af, *(const f16x8*)(wb + cb * 16 * FIN + k0), acc[cb], 0, 0, 0);
  }
  if (kh == 1) {
    float* q = red + (jb * 64 + lane) * 20;
#pragma unroll
    for (int cb = 0; cb < 4; ++cb) *(f32x4*)(q + cb * 4) = acc[cb];
  }
  __syncthreads();
  if (kh == 0) {
    const float* q = red + (jb * 64 + lane) * 20;
#pragma unroll
    for (int cb = 0; cb < 4; ++cb) acc[cb] += *(const f32x4*)(q + cb * 4);
    // Whfrag[h][jt][cb][l][e] = Wh[jt*32 + (l>>4)*8 + e][cb*16 + (l&15)]
    int jt = i0 >> 5;
    int kk0 = (i0 & 31) + grp * 4;
    int tl = (kk0 >> 3) * 16 + row16;
    int e0 = kk0 & 7;
#pragma unroll
    for (int cb = 0; cb < 4; ++cb) {
      ushort4 pk;
      pk.x = f2h(acc[cb][0]); pk.y = f2h(acc[cb][1]);
      pk.z = f2h(acc[cb][2]); pk.w = f2h(acc[cb][3]);
      *(ushort4*)(Whfrag + (((size_t)h * 128 + jt) * 4 + cb) * 512 + tl * 8 + e0) = pk;
    }
  }
}

// ---------------- gat: register-direct quad-af; adj staged to padded LDS ----------
struct Tile {
  f16x8 b0, b1, b2, b3;    // B-fragments (16 VGPR)
  f16x8 e1, e2;            // E tables    (8 VGPR)
};

#define ROWW 132            // padded words/row: bank = (row*4 + jt) % 32 -> 2-way free

__global__ __launch_bounds__(256, 2) void gat_kernel(
    const unsigned* __restrict__ adjbits, const unsigned short* __restrict__ Whfrag,
    const float* __restrict__ Rf, const unsigned short* __restrict__ E1h,
    const unsigned short* __restrict__ E2h, float* __restrict__ out) {
  __shared__ __align__(16) char lds[64 * ROWW * 4];   // 33792 B: adj stage / reduce overlay
  unsigned* la = (unsigned*)lds;
  int h = blockIdx.y;
  int lane = threadIdx.x & 63, jseg = threadIdx.x >> 6;
  int row16 = lane & 15, grp = lane >> 4;
  int r0 = blockIdx.x * 64;
  int jt0 = jseg * 32;

  // ---- stage adj rows r0..r0+63 (row-major, 128 words each) -> LDS, coalesced ----
  {
    int row = threadIdx.x >> 2, seg = threadIdx.x & 3;   // thread reads 128B row-chunk
    const uint4* src = (const uint4*)(adjbits + (size_t)(r0 + row) * 128 + seg * 32);
    uint4* dst = (uint4*)(la + row * ROWW + seg * 32);
#pragma unroll
    for (int i = 0; i < 8; ++i) dst[i] = src[i];
  }

  f16x2 Rh[4];
#pragma unroll
  for (int gi = 0; gi < 4; ++gi) {
    _Float16 rv = (_Float16)Rf[h * NN + r0 + gi * 16 + row16];
    Rh[gi][0] = rv; Rh[gi][1] = rv;
  }

  H8 ones;
#pragma unroll
  for (int k = 0; k < 4; ++k) ones.u[k] = 0x3C003C00u;   // fp16 1.0 pairs

  const unsigned short* wsrc = Whfrag + (size_t)h * 262144 + (size_t)jt0 * 2048 + lane * 8;
  const unsigned short* e1p = E1h + h * NN + jt0 * 32 + grp * 8;
  const unsigned short* e2p = E2h + h * NN + jt0 * 32 + grp * 8;

  f32x4 acc[4][5];
#pragma unroll
  for (int gi = 0; gi < 4; ++gi)
#pragma unroll
    for (int cc = 0; cc < 5; ++cc) acc[gi][cc] = (f32x4){0, 0, 0, 0};

  __syncthreads();                        // adj stage visible to all waves

  auto ld = [&](int p, Tile& t) {          // 6 L2-hot loads -> VGPRs
    const unsigned short* bs = wsrc + (size_t)p * 2048;
    t.b0 = *(const f16x8*)(bs);
    t.b1 = *(const f16x8*)(bs + 512);
    t.b2 = *(const f16x8*)(bs + 1024);
    t.b3 = *(const f16x8*)(bs + 1536);
    t.e1 = *(const f16x8*)(e1p + p * 32);
    t.e2 = *(const f16x8*)(e2p + p * 32);
  };

  auto compute = [&](int p, const Tile& t) {
    H8 e1, e2;
    e1.v = t.e1; e2.v = t.e2;
    int jt = jt0 + p;
#pragma unroll
    for (int gi = 0; gi < 4; ++gi) {
      unsigned bw = la[(gi * 16 + row16) * ROWW + jt];   // conflict-free ds_read
      unsigned bb = (bw >> (grp * 8)) & 0xffu;
      unsigned tt = bb | (bb << 15);       // bit k at {k, k+15}
      H8 af;
#pragma unroll
      for (int k = 0; k < 4; ++k) {
        f16x2 mx = __builtin_elementwise_max(e1.p[k], Rh[gi] * e2.p[k]);
        U2 m;                              // bit2k->pos14, bit2k+1->pos30 (fp16 2.0)
        m.u = (tt << (14 - 2 * k)) & 0x40004000u;
        af.p[k] = mx * m.v;
      }
      acc[gi][0] = __builtin_amdgcn_mfma_f32_16x16x32_f16(af.v, t.b0, acc[gi][0], 0, 0, 0);
      acc[gi][1] = __builtin_amdgcn_mfma_f32_16x16x32_f16(af.v, t.b1, acc[gi][1], 0, 0, 0);
      acc[gi][2] = __builtin_amdgcn_mfma_f32_16x16x32_f16(af.v, t.b2, acc[gi][2], 0, 0, 0);
      acc[gi][3] = __builtin_amdgcn_mfma_f32_16x16x32_f16(af.v, t.b3, acc[gi][3], 0, 0, 0);
      acc[gi][4] = __builtin_amdgcn_mfma_f32_16x16x32_f16(af.v, ones.v, acc[gi][4], 0, 0, 0);
    }
  };

  // ---- barrier-free register pipeline: loads pinned above compute by mem-fence ----
  Tile tA, tB;
  ld(0, tA);
#pragma unroll 1
  for (int p2 = 0; p2 < 15; ++p2) {
    ld(2 * p2 + 1, tB);
    asm volatile("" ::: "memory");         // compute reads LDS -> fence effective here
    compute(2 * p2, tA);
    ld(2 * p2 + 2, tA);
    asm volatile("" ::: "memory");
    compute(2 * p2 + 1, tB);
  }
  ld(31, tB);
  compute(30, tA);
  compute(31, tB);

  // ---- chunked cross-jseg reduction (overlay onto adj LDS, static indices) ----
  __syncthreads();
  float* red = (float*)lds;               // 12 KB of the 33 KB
#pragma unroll
  for (int cc = 0; cc < 5; ++cc) {
    if (jseg != 0) {
#pragma unroll
      for (int gi = 0; gi < 4; ++gi)
        *(f32x4*)(red + (((jseg - 1) * 4 + gi) * 64 + lane) * 4) = acc[gi][cc];
    }
    __syncthreads();
    if (jseg == 0) {
#pragma unroll
      for (int s = 0; s < 3; ++s)
#pragma unroll
        for (int gi = 0; gi < 4; ++gi)
          acc[gi][cc] += *(const f32x4*)(red + ((s * 4 + gi) * 64 + lane) * 4);
    }
    __syncthreads();
  }

  if (jseg == 0) {
#pragma unroll
    for (int gi = 0; gi < 4; ++gi) {
#pragma unroll
      for (int reg = 0; reg < 4; ++reg) {
        float inv = 1.0f / acc[gi][4][reg];
        int row = r0 + gi * 16 + grp * 4 + reg;
        float* op = out + (size_t)row * (NH * FO) + h * FO + row16;
        op[0]  = acc[gi][0][reg] * inv;
        op[16] = acc[gi][1][reg] * inv;
        op[32] = acc[gi][2][reg] * inv;
        op[48] = acc[gi][3][reg] * inv;
      }
    }
  }
}

extern "C" void kernel_launch(void* const* d_in, const int* in_sizes, int n_in,
                              void* d_out, int out_size, void* d_ws, size_t ws_size,
                              hipStream_t stream) {
  const float* X  = (const float*)d_in[0];
  const int* adj  = (const int*)d_in[1];
  const float* W  = (const float*)d_in[2];
  const float* a  = (const float*)d_in[3];
  float* out = (float*)d_out;
  char* ws = (char*)d_ws;

  unsigned short* WbT    = (unsigned short*)(ws + 0);          // 512 KB
  unsigned* adjbits      = (unsigned*)(ws + 524288);           // 2 MB, row-major [r][jt]
  unsigned short* Whfrag = (unsigned short*)(ws + 2621440);    // 4 MB
  unsigned short* WAh    = (unsigned short*)(ws + 6815744);    // 16 KB
  float* Rf              = (float*)(ws + 6832128);             // 128 KB
  unsigned short* E1h    = (unsigned short*)(ws + 6963200);    // 64 KB
  unsigned short* E2h    = (unsigned short*)(ws + 7028736);    // 64 KB
  unsigned short* Xh     = (unsigned short*)(ws + 7094272);    // 4 MB (total ~10.8 MB)

  prep_pack_kernel<<<5152, 256, 0, stream>>>(W, a, X, adj, WbT, WAh, Xh, adjbits);
  proj_sd_kernel<<<544, 512, 0, stream>>>(Xh, WbT, WAh, Whfrag, Rf, E1h, E2h);
  gat_kernel<<<dim3(64, 8), 256, 0, stream>>>(adjbits, Whfrag, Rf, E1h, E2h, out);
}

// Round 30
// 73.375 us; speedup vs baseline: 1.0408x; 1.0408x over previous
//
#include <hip/hip_runtime.h>
#include <stdint.h>

// GAT: N=4096, F_in=512, H=8, F_out=64.
// P_ij = A_i·max(E1_j, R_i·E2_j)·adj, R_i = e^{-0.8 s_i}; A_i cancels in softmax.
// Round 30: r28 base + gat prefetch DEPTH-2 (triple-buffered tA/tB/tC tiles,
// 12 loads in flight per wave vs 6 — 2x latency coverage at 2 waves/SIMD).
// ~190 VGPR fits (256,2)'s 256 cap. Everything else identical to r28 (73.5us).

#define NN 4096
#define FIN 512
#define NH 8
#define FO 64

typedef _Float16 f16x8 __attribute__((ext_vector_type(8)));
typedef _Float16 f16x2 __attribute__((ext_vector_type(2)));
typedef __attribute__((ext_vector_type(4))) float f32x4;

union H8 { f16x8 v; f16x2 p[4]; unsigned u[4]; };
union U2 { unsigned u; f16x2 v; };

__device__ __forceinline__ unsigned short f2h(float f) {
  _Float16 h = (_Float16)f;               // RNE
  return __builtin_bit_cast(unsigned short, h);
}

// ---------------- prep_w: W->WbT, wa = W^T a, X->Xh ------------------------------
__global__ __launch_bounds__(256) void prep_w_kernel(
    const float* __restrict__ W, const float* __restrict__ a, const float* __restrict__ X,
    unsigned short* __restrict__ WbT, unsigned short* __restrict__ WAh,
    unsigned short* __restrict__ Xh) {
  int bid = blockIdx.x, tid = threadIdx.x;
  if (bid < 1024) {                       // W[h][k][o] -> WbT[h][o][k], coalesced READ
    int item = bid * 256 + tid;           // 262144 items = (h,k,o)
    int o = item & 63, k = (item >> 6) & 511, h = item >> 15;
    WbT[h * 32768 + o * 512 + k] = f2h(W[h * 32768 + k * 64 + o]);
  } else if (bid < 1056) {                // wa[t][k] = sum_o W[h][k][o]*a[h][which*64+o]
    int item = (bid - 1024) * 256 + tid;  // 8192 items: t = h*2+which, k
    int h = item >> 10, which = (item >> 9) & 1, k = item & 511;
    const float4* wp = (const float4*)(W + ((size_t)h * FIN + k) * FO);
    const float4* ap = (const float4*)(a + h * 128 + which * 64);
    float s = 0.f;
#pragma unroll
    for (int o4 = 0; o4 < 16; ++o4) {
      float4 w4 = wp[o4], a4 = ap[o4];
      s += w4.x * a4.x + w4.y * a4.y + w4.z * a4.z + w4.w * a4.w;
    }
    WAh[(h * 2 + which) * FIN + k] = f2h(s);
  } else {                                // X -> fp16, float4/thread
    int item = (bid - 1056) * 256 + tid;  // 524288 items
    float4 v = ((const float4*)X)[item];
    ushort4 o;
    o.x = f2h(v.x); o.y = f2h(v.y); o.z = f2h(v.z); o.w = f2h(v.w);
    ((ushort4*)Xh)[item] = o;
  }
}

// ---------------- fused: proj bx<256 | sd bx<288 | adj-pack bx>=288 ---------------
// D layout (16x16x32): col = lane&15, row = (lane>>4)*4 + reg   [m89]
__global__ __launch_bounds__(512, 4) void proj_adj_kernel(
    const unsigned short* __restrict__ Xh, const int* __restrict__ adj,
    const unsigned short* __restrict__ WbT, const unsigned short* __restrict__ WAh,
    unsigned short* __restrict__ Whfrag, float* __restrict__ Rf,
    unsigned short* __restrict__ E1h, unsigned short* __restrict__ E2h,
    unsigned* __restrict__ adjbits) {
  __shared__ __align__(16) unsigned lw[8 * 1056];   // 33792 B (pack blocks only)
  int lane = threadIdx.x & 63, wave = threadIdx.x >> 6;
  int row16 = lane & 15, grp = lane >> 4;
  int bx = blockIdx.x;
  if (bx >= 288) {                        // ---- adj-pack: LDS-transpose, coalesced
    int item0 = (bx - 288) * 512 + wave * 64;      // wave owns 64 output words
    unsigned* w = lw + wave * 1056;                // wave-private padded slab
#pragma unroll
    for (int pass = 0; pass < 2; ++pass) {
      int ib = item0 + pass * 32;                  // 32 words = 4KB of adj
      const uint4* src = (const uint4*)adj + (size_t)ib * 8;
      uint4 tmp[4];
#pragma unroll
      for (int i = 0; i < 4; ++i) tmp[i] = src[i * 64 + lane];   // 1KB/instr coalesced
#pragma unroll
      for (int i = 0; i < 4; ++i) {
        int q = i * 64 + lane;                     // q = item*8 + chunk
        *(uint4*)(w + (q >> 3) * 33 + (q & 7) * 4) = tmp[i];
      }
      asm volatile("s_waitcnt lgkmcnt(0)" ::: "memory");   // wave-internal drain
      if (lane < 32) {
        unsigned bits = 0;
#pragma unroll
        for (int c = 0; c < 8; ++c) {              // conflict-free: bank = lane+4c
          uint4 v = *(const uint4*)(w + lane * 33 + c * 4);
          bits |= (unsigned)(v.x & 1) << (4 * c);
          bits |= (unsigned)(v.y & 1) << (4 * c + 1);
          bits |= (unsigned)(v.z & 1) << (4 * c + 2);
          bits |= (unsigned)(v.w & 1) << (4 * c + 3);
        }
        adjbits[ib + lane] = bits;                 // 128B contiguous store
      }
    }
    return;
  }
  if (bx >= 256) {                        // sd: [s,d]x8 = Xh @ WA  (16 cols, K=512)
    int i0 = ((bx - 256) * 8 + wave) * 16;
    if (i0 >= NN) return;
    f32x4 acc = {0, 0, 0, 0};
    const unsigned short* xb = Xh + (size_t)(i0 + row16) * FIN + grp * 8;
    const unsigned short* wb = WAh + row16 * FIN + grp * 8;
#pragma unroll
    for (int k0 = 0; k0 < FIN; k0 += 32)
      acc = __builtin_amdgcn_mfma_f32_16x16x32_f16(*(const f16x8*)(xb + k0),
                                                   *(const f16x8*)(wb + k0), acc, 0, 0, 0);
    int hh = row16 >> 1;
#pragma unroll
    for (int reg = 0; reg < 4; ++reg) {
      int rr = i0 + grp * 4 + reg;
      float v = acc[reg];
      if (row16 & 1) {                    // d -> col tables fp16, PRE-HALVED
        E1h[hh * NN + rr] = f2h(0.5f * __expf(v));
        E2h[hh * NN + rr] = f2h(0.5f * __expf(0.2f * v));
      } else {                            // s -> row table R = e^{-0.8 s}
        Rf[hh * NN + rr] = __expf(-0.8f * v);
      }
    }
    return;
  }
  // ---- proj: wave = one (rowtile, head) job, K=512, sched_barrier-pinned pipeline
  int job = bx * 8 + wave;                // 2048 jobs = 256 rowtiles x 8 heads
  int h = job & 7, rt = job >> 3;
  int i0 = rt * 16;
  const unsigned short* xb = Xh + (size_t)(i0 + row16) * FIN + grp * 8;
  const unsigned short* wb = WbT + h * (FO * FIN) + row16 * FIN + grp * 8;
  f32x4 acc[4] = {{0,0,0,0},{0,0,0,0},{0,0,0,0},{0,0,0,0}};

  f16x8 xA, xB, w0A, w1A, w2A, w3A, w0B, w1B, w2B, w3B;
#define PLD(S, p)                                                     \
  {                                                                   \
    x##S  = *(const f16x8*)(xb + (p) * 32);                           \
    w0##S = *(const f16x8*)(wb + 0 * 16 * FIN + (p) * 32);            \
    w1##S = *(const f16x8*)(wb + 1 * 16 * FIN + (p) * 32);            \
    w2##S = *(const f16x8*)(wb + 2 * 16 * FIN + (p) * 32);            \
    w3##S = *(const f16x8*)(wb + 3 * 16 * FIN + (p) * 32);            \
  }
#define PCMP(S)                                                       \
  {                                                                   \
    acc[0] = __builtin_amdgcn_mfma_f32_16x16x32_f16(x##S, w0##S, acc[0], 0, 0, 0); \
    acc[1] = __builtin_amdgcn_mfma_f32_16x16x32_f16(x##S, w1##S, acc[1], 0, 0, 0); \
    acc[2] = __builtin_amdgcn_mfma_f32_16x16x32_f16(x##S, w2##S, acc[2], 0, 0, 0); \
    acc[3] = __builtin_amdgcn_mfma_f32_16x16x32_f16(x##S, w3##S, acc[3], 0, 0, 0); \
  }
  PLD(A, 0)
#pragma unroll 1
  for (int p2 = 0; p2 < 7; ++p2) {
    PLD(B, 2 * p2 + 1)
    __builtin_amdgcn_sched_barrier(0);     // pin: B-loads issued before A-compute
    PCMP(A)
    __builtin_amdgcn_sched_barrier(0);
    PLD(A, 2 * p2 + 2)
    __builtin_amdgcn_sched_barrier(0);
    PCMP(B)
    __builtin_amdgcn_sched_barrier(0);
  }
  PLD(B, 15)
  __builtin_amdgcn_sched_barrier(0);
  PCMP(A)
  PCMP(B)
#undef PLD
#undef PCMP
  // Whfrag[h][jt][cb][l][e] = Wh[jt*32 + (l>>4)*8 + e][cb*16 + (l&15)]
  int jt = i0 >> 5;
  int kk0 = (i0 & 31) + grp * 4;
  int tl = (kk0 >> 3) * 16 + row16;
  int e0 = kk0 & 7;
#pragma unroll
  for (int cb = 0; cb < 4; ++cb) {
    ushort4 pk;
    pk.x = f2h(acc[cb][0]); pk.y = f2h(acc[cb][1]);
    pk.z = f2h(acc[cb][2]); pk.w = f2h(acc[cb][3]);
    *(ushort4*)(Whfrag + (((size_t)h * 128 + jt) * 4 + cb) * 512 + tl * 8 + e0) = pk;
  }
}

// ---------------- gat: register-direct quad-af, DEPTH-2 prefetch ------------------
struct Tile {
  f16x8 b0, b1, b2, b3;    // B-fragments (16 VGPR)
  f16x8 e1, e2;            // E tables    (8 VGPR)
};

#define ROWW 132            // padded words/row: bank = (row*4 + jt) % 32 -> 2-way free

__global__ __launch_bounds__(256, 2) void gat_kernel(
    const unsigned* __restrict__ adjbits, const unsigned short* __restrict__ Whfrag,
    const float* __restrict__ Rf, const unsigned short* __restrict__ E1h,
    const unsigned short* __restrict__ E2h, float* __restrict__ out) {
  __shared__ __align__(16) char lds[64 * ROWW * 4];   // 33792 B: adj stage / reduce overlay
  unsigned* la = (unsigned*)lds;
  int h = blockIdx.y;
  int lane = threadIdx.x & 63, jseg = threadIdx.x >> 6;
  int row16 = lane & 15, grp = lane >> 4;
  int r0 = blockIdx.x * 64;
  int jt0 = jseg * 32;

  // ---- stage adj rows r0..r0+63 (row-major, 128 words each) -> LDS, coalesced ----
  {
    int row = threadIdx.x >> 2, seg = threadIdx.x & 3;   // thread reads 128B row-chunk
    const uint4* src = (const uint4*)(adjbits + (size_t)(r0 + row) * 128 + seg * 32);
    uint4* dst = (uint4*)(la + row * ROWW + seg * 32);
#pragma unroll
    for (int i = 0; i < 8; ++i) dst[i] = src[i];
  }

  f16x2 Rh[4];
#pragma unroll
  for (int gi = 0; gi < 4; ++gi) {
    _Float16 rv = (_Float16)Rf[h * NN + r0 + gi * 16 + row16];
    Rh[gi][0] = rv; Rh[gi][1] = rv;
  }

  H8 ones;
#pragma unroll
  for (int k = 0; k < 4; ++k) ones.u[k] = 0x3C003C00u;   // fp16 1.0 pairs

  const unsigned short* wsrc = Whfrag + (size_t)h * 262144 + (size_t)jt0 * 2048 + lane * 8;
  const unsigned short* e1p = E1h + h * NN + jt0 * 32 + grp * 8;
  const unsigned short* e2p = E2h + h * NN + jt0 * 32 + grp * 8;

  f32x4 acc[4][5];
#pragma unroll
  for (int gi = 0; gi < 4; ++gi)
#pragma unroll
    for (int cc = 0; cc < 5; ++cc) acc[gi][cc] = (f32x4){0, 0, 0, 0};

  __syncthreads();                        // adj stage visible to all waves

  auto ld = [&](int p, Tile& t) {          // 6 L2-hot loads -> VGPRs
    const unsigned short* bs = wsrc + (size_t)p * 2048;
    t.b0 = *(const f16x8*)(bs);
    t.b1 = *(const f16x8*)(bs + 512);
    t.b2 = *(const f16x8*)(bs + 1024);
    t.b3 = *(const f16x8*)(bs + 1536);
    t.e1 = *(const f16x8*)(e1p + p * 32);
    t.e2 = *(const f16x8*)(e2p + p * 32);
  };

  auto compute = [&](int p, const Tile& t) {
    H8 e1, e2;
    e1.v = t.e1; e2.v = t.e2;
    int jt = jt0 + p;
#pragma unroll
    for (int gi = 0; gi < 4; ++gi) {
      unsigned bw = la[(gi * 16 + row16) * ROWW + jt];   // conflict-free ds_read
      unsigned bb = (bw >> (grp * 8)) & 0xffu;
      unsigned tt = bb | (bb << 15);       // bit k at {k, k+15}
      H8 af;
#pragma unroll
      for (int k = 0; k < 4; ++k) {
        f16x2 mx = __builtin_elementwise_max(e1.p[k], Rh[gi] * e2.p[k]);
        U2 m;                              // bit2k->pos14, bit2k+1->pos30 (fp16 2.0)
        m.u = (tt << (14 - 2 * k)) & 0x40004000u;
        af.p[k] = mx * m.v;
      }
      acc[gi][0] = __builtin_amdgcn_mfma_f32_16x16x32_f16(af.v, t.b0, acc[gi][0], 0, 0, 0);
      acc[gi][1] = __builtin_amdgcn_mfma_f32_16x16x32_f16(af.v, t.b1, acc[gi][1], 0, 0, 0);
      acc[gi][2] = __builtin_amdgcn_mfma_f32_16x16x32_f16(af.v, t.b2, acc[gi][2], 0, 0, 0);
      acc[gi][3] = __builtin_amdgcn_mfma_f32_16x16x32_f16(af.v, t.b3, acc[gi][3], 0, 0, 0);
      acc[gi][4] = __builtin_amdgcn_mfma_f32_16x16x32_f16(af.v, ones.v, acc[gi][4], 0, 0, 0);
    }
  };

  // ---- depth-2 register pipeline: 12 loads in flight, fences order vs LDS reads ---
  Tile tA, tB, tC;
  ld(0, tA);
  ld(1, tB);
#pragma unroll 1
  for (int p3 = 0; p3 < 10; ++p3) {
    int base = p3 * 3;
    ld(base + 2, tC);
    asm volatile("" ::: "memory");
    compute(base, tA);
    ld(base + 3, tA);
    asm volatile("" ::: "memory");
    compute(base + 1, tB);
    ld(base + 4, tB);
    asm volatile("" ::: "memory");
    compute(base + 2, tC);
  }
  compute(30, tA);                         // loaded in final iter (base+3 = 30)
  compute(31, tB);                         // loaded in final iter (base+4 = 31)

  // ---- chunked cross-jseg reduction (overlay onto adj LDS, static indices) ----
  __syncthreads();
  float* red = (float*)lds;               // 12 KB of the 33 KB
#pragma unroll
  for (int cc = 0; cc < 5; ++cc) {
    if (jseg != 0) {
#pragma unroll
      for (int gi = 0; gi < 4; ++gi)
        *(f32x4*)(red + (((jseg - 1) * 4 + gi) * 64 + lane) * 4) = acc[gi][cc];
    }
    __syncthreads();
    if (jseg == 0) {
#pragma unroll
      for (int s = 0; s < 3; ++s)
#pragma unroll
        for (int gi = 0; gi < 4; ++gi)
          acc[gi][cc] += *(const f32x4*)(red + ((s * 4 + gi) * 64 + lane) * 4);
    }
    __syncthreads();
  }

  if (jseg == 0) {
#pragma unroll
    for (int gi = 0; gi < 4; ++gi) {
#pragma unroll
      for (int reg = 0; reg < 4; ++reg) {
        float inv = 1.0f / acc[gi][4][reg];
        int row = r0 + gi * 16 + grp * 4 + reg;
        float* op = out + (size_t)row * (NH * FO) + h * FO + row16;
        op[0]  = acc[gi][0][reg] * inv;
        op[16] = acc[gi][1][reg] * inv;
        op[32] = acc[gi][2][reg] * inv;
        op[48] = acc[gi][3][reg] * inv;
      }
    }
  }
}

extern "C" void kernel_launch(void* const* d_in, const int* in_sizes, int n_in,
                              void* d_out, int out_size, void* d_ws, size_t ws_size,
                              hipStream_t stream) {
  const float* X  = (const float*)d_in[0];
  const int* adj  = (const int*)d_in[1];
  const float* W  = (const float*)d_in[2];
  const float* a  = (const float*)d_in[3];
  float* out = (float*)d_out;
  char* ws = (char*)d_ws;

  unsigned short* WbT    = (unsigned short*)(ws + 0);          // 512 KB
  unsigned* adjbits      = (unsigned*)(ws + 524288);           // 2 MB, row-major [r][jt]
  unsigned short* Whfrag = (unsigned short*)(ws + 2621440);    // 4 MB
  unsigned short* WAh    = (unsigned short*)(ws + 6815744);    // 16 KB
  float* Rf              = (float*)(ws + 6832128);             // 128 KB
  unsigned short* E1h    = (unsigned short*)(ws + 6963200);    // 64 KB
  unsigned short* E2h    = (unsigned short*)(ws + 7028736);    // 64 KB
  unsigned short* Xh     = (unsigned short*)(ws + 7094272);    // 4 MB (total ~10.8 MB)

  prep_w_kernel<<<3104, 256, 0, stream>>>(W, a, X, WbT, WAh, Xh);
  proj_adj_kernel<<<1312, 512, 0, stream>>>(Xh, adj, WbT, WAh, Whfrag, Rf, E1h, E2h,
                                            adjbits);
  gat_kernel<<<dim3(64, 8), 256, 0, stream>>>(adjbits, Whfrag, Rf, E1h, E2h, out);
}